// Round 3
// baseline (1391.716 us; speedup 1.0000x reference)
//
#include <hip/hip_runtime.h>

// Problem constants (B=2, T=64 -> N=128 images; C=O=16; H=W=128; nh=8, hc=2, D=32768)
#define NIMG 128
#define CH   16
#define HPIX 128
#define WPIX 128
#define HW   16384          // 128*128
#define NHEAD 8
#define TT   64             // tokens
#define DHEAD 32768         // 2*HW
#define QSZ  33554432       // NIMG*CH*HW floats per q/k/v buffer
#define NSLICE 32
#define SCALE_ATT 0.0055242717280199f  // 1/sqrt(32768)

// conv spatial tile
#define TH 4
#define TW 64

// ---------------- conv 3x3 (pad 1), NC=3 for fused QKV, NC=1 for output conv ----------
// __launch_bounds__(256, 4): 4 blocks/CU -> 128-VGPR cap. Round-2 profile showed
// VGPR_Count=40 with 48 live accumulators -> compiler shuffled acc through AGPRs
// (~4x VALU instructions per useful FMA). 128 VGPRs fits 48 acc + 9 xv + addressing.
template<int NC>
__global__ __launch_bounds__(256, 4) void conv3x3_k(
    const float* __restrict__ xin,
    const float* __restrict__ w0c, const float* __restrict__ b0c,
    const float* __restrict__ w1c, const float* __restrict__ b1c,
    const float* __restrict__ w2c, const float* __restrict__ b2c,
    float* __restrict__ o0, float* __restrict__ o1, float* __restrict__ o2)
{
    __shared__ float xs[CH][TH+2][TW+2];
    const int bid = blockIdx.x;
    const int wt = bid & 1;          // WPIX/TW = 2
    const int ht = (bid >> 1) & 31;  // HPIX/TH = 32
    const int n  = bid >> 6;         // image
    const int h0 = ht*TH, w0 = wt*TW;
    const int tid = threadIdx.x;

    const int PATCH = CH*(TH+2)*(TW+2);   // 16*6*66 = 6336
    for (int i = tid; i < PATCH; i += 256) {
        int cc = i % (TW+2);
        int r  = (i/(TW+2)) % (TH+2);
        int ic = i / ((TW+2)*(TH+2));
        int gh = h0 + r - 1, gw = w0 + cc - 1;
        float val = 0.f;
        if ((unsigned)gh < (unsigned)HPIX && (unsigned)gw < (unsigned)WPIX)
            val = xin[((n*CH + ic)*HPIX + gh)*WPIX + gw];
        xs[ic][r][cc] = val;
    }
    __syncthreads();

    const int tx = tid & 63, ty = tid >> 6;
    float a0[16], a1[16], a2[16];
    #pragma unroll
    for (int oc = 0; oc < 16; ++oc) {
        a0[oc] = b0c[oc];
        if constexpr (NC > 1) { a1[oc] = b1c[oc]; a2[oc] = b2c[oc]; }
    }

    for (int ic = 0; ic < 16; ++ic) {
        float xv[9];
        #pragma unroll
        for (int r = 0; r < 3; ++r)
            #pragma unroll
            for (int c = 0; c < 3; ++c)
                xv[r*3+c] = xs[ic][ty+r][tx+c];
        #pragma unroll
        for (int oc = 0; oc < 16; ++oc) {
            const int wb = (oc*16 + ic)*9;   // uniform -> scalar loads
            #pragma unroll
            for (int j = 0; j < 9; ++j) {
                a0[oc] = fmaf(xv[j], w0c[wb+j], a0[oc]);
                if constexpr (NC > 1) {
                    a1[oc] = fmaf(xv[j], w1c[wb+j], a1[oc]);
                    a2[oc] = fmaf(xv[j], w2c[wb+j], a2[oc]);
                }
            }
        }
    }

    const int h = h0 + ty, w = w0 + tx;
    #pragma unroll
    for (int oc = 0; oc < 16; ++oc) {
        int idx = ((n*CH + oc)*HPIX + h)*WPIX + w;
        o0[idx] = a0[oc];
        if constexpr (NC > 1) { o1[idx] = a1[oc]; o2[idx] = a2[oc]; }
    }
}

// ---------------- QK^T partial sums over d-slices --------------------------------------
// grid = 16 bh * NSLICE; each block: 64x64 scores partial over 512 pix * 2 ch.
__global__ __launch_bounds__(256, 4) void qk_partial_k(
    const float* __restrict__ q, const float* __restrict__ k,
    float* __restrict__ partial)
{
    __shared__ float qs[64][65];
    __shared__ float ks[64][65];
    const int slice = blockIdx.x & (NSLICE-1);
    const int bh = blockIdx.x >> 5;
    const int b = bh >> 3, h = bh & 7;
    const int tid = threadIdx.x;
    const int ss = (tid & 15) * 4;
    const int tt = (tid >> 4) * 4;

    float acc[4][4];
    #pragma unroll
    for (int i = 0; i < 4; ++i)
        #pragma unroll
        for (int j = 0; j < 4; ++j) acc[i][j] = 0.f;

    for (int c = 0; c < 2; ++c) {
        for (int pc = 0; pc < 8; ++pc) {       // 8 chunks of 64 pix -> 512 pix/slice
            const int pixbase = slice*512 + pc*64;
            __syncthreads();
            for (int i = tid; i < 4096; i += 256) {
                int t = i >> 6, p = i & 63;
                int gidx = ((b*TT + t)*CH + 2*h + c)*HW + pixbase + p;
                qs[t][p] = q[gidx];
                ks[t][p] = k[gidx];
            }
            __syncthreads();
            for (int p = 0; p < 64; ++p) {
                float q4[4], k4[4];
                #pragma unroll
                for (int i = 0; i < 4; ++i) { q4[i] = qs[tt+i][p]; k4[i] = ks[ss+i][p]; }
                #pragma unroll
                for (int i = 0; i < 4; ++i)
                    #pragma unroll
                    for (int j = 0; j < 4; ++j)
                        acc[i][j] = fmaf(q4[i], k4[j], acc[i][j]);
            }
        }
    }

    float* pp = partial + (size_t)blockIdx.x * 4096;   // [bh][slice][t][s]
    #pragma unroll
    for (int i = 0; i < 4; ++i)
        #pragma unroll
        for (int j = 0; j < 4; ++j)
            pp[(tt+i)*64 + (ss+j)] = acc[i][j];
}

// ---------------- reduce partials -> logits --------------------------------------------
__global__ __launch_bounds__(256) void reduce_logits_k(
    const float* __restrict__ partial, float* __restrict__ logits)
{
    int idx = blockIdx.x * 256 + threadIdx.x;   // [0, 16*4096)
    int bh = idx >> 12, ts = idx & 4095;
    float s = 0.f;
    for (int sl = 0; sl < NSLICE; ++sl)
        s += partial[((size_t)(bh*NSLICE) + sl)*4096 + ts];
    logits[idx] = s;
}

// ---------------- causal softmax; writes att TRANSPOSED: att[bh][s][t] -----------------
__global__ __launch_bounds__(256) void softmax_k(
    const float* __restrict__ logits, float* __restrict__ att)
{
    const int bh = blockIdx.x;
    const int tid = threadIdx.x;
    const int t = tid >> 2, sg = tid & 3;       // 4 lanes cooperate on one row t
    float r[16];
    #pragma unroll
    for (int i = 0; i < 16; ++i) {
        int s = sg*16 + i;
        float val = logits[bh*4096 + t*64 + s] * SCALE_ATT;
        r[i] = (s <= t) ? val : -1e30f;
    }
    float m = r[0];
    #pragma unroll
    for (int i = 1; i < 16; ++i) m = fmaxf(m, r[i]);
    m = fmaxf(m, __shfl_xor(m, 1));
    m = fmaxf(m, __shfl_xor(m, 2));
    float sum = 0.f;
    #pragma unroll
    for (int i = 0; i < 16; ++i) {
        int s = sg*16 + i;
        r[i] = (s <= t) ? expf(r[i] - m) : 0.f;
        sum += r[i];
    }
    sum += __shfl_xor(sum, 1);
    sum += __shfl_xor(sum, 2);
    const float inv = 1.f / sum;
    #pragma unroll
    for (int i = 0; i < 16; ++i) {
        int s = sg*16 + i;
        att[(bh*64 + s)*64 + t] = r[i] * inv;   // transposed for uniform reads in attv
    }
}

// ---------------- y = att @ v, written directly in conv layout [n][oc][pix] ------------
// grid = 16 bh * 128 chunks; thread owns one d (c,pix), accumulates all 64 t.
// launch_bounds(256,2): 64 accumulators + addressing needs ~90 VGPRs -> 256-cap is safe,
// 2 blocks/CU = 8 waves/CU is enough for a streaming kernel with 64-deep ILP.
__global__ __launch_bounds__(256, 2) void attv_k(
    const float* __restrict__ v, const float* __restrict__ att,
    float* __restrict__ y)
{
    const int chunk = blockIdx.x & 127;
    const int bh = blockIdx.x >> 7;
    const int b = bh >> 3, h = bh & 7;
    const int d = chunk*256 + threadIdx.x;      // [0, 32768)
    const int c = d >> 14, pix = d & (HW-1);
    const float* vp = v + ((size_t)(b*TT)*CH + 2*h + c)*HW + pix;
    const float* ap = att + bh*4096;            // attT[s][t]
    float acc[64];
    #pragma unroll
    for (int t = 0; t < 64; ++t) acc[t] = 0.f;
    for (int s = 0; s < 64; ++s) {
        float vv = vp[(size_t)s*CH*HW];
        #pragma unroll
        for (int t = 0; t < 64; ++t)
            acc[t] = fmaf(ap[s*64 + t], vv, acc[t]);   // uniform -> scalar loads
    }
    float* yp = y + ((size_t)(b*TT)*CH + 2*h + c)*HW + pix;
    #pragma unroll
    for (int t = 0; t < 64; ++t)
        yp[(size_t)t*CH*HW] = acc[t];
}

// ---------------- launch ---------------------------------------------------------------
extern "C" void kernel_launch(void* const* d_in, const int* in_sizes, int n_in,
                              void* d_out, int out_size, void* d_ws, size_t ws_size,
                              hipStream_t stream)
{
    const float* x  = (const float*)d_in[0];
    const float* wq = (const float*)d_in[1];
    const float* bq = (const float*)d_in[2];
    const float* wk = (const float*)d_in[3];
    const float* bk = (const float*)d_in[4];
    const float* wv = (const float*)d_in[5];
    const float* bv = (const float*)d_in[6];
    const float* wo = (const float*)d_in[7];
    const float* bo = (const float*)d_in[8];
    float* out = (float*)d_out;

    float* ws = (float*)d_ws;
    float* q = ws;
    float* k = ws + QSZ;
    float* v = ws + 2*(size_t)QSZ;
    float* partial = ws + 3*(size_t)QSZ;            // 16*32*4096 = 2,097,152 floats
    float* logits  = partial + 16*NSLICE*4096;      // 65,536 floats
    float* att     = logits + 65536;                // 65,536 floats
    float* y = q;                                   // q is dead after softmax

    conv3x3_k<3><<<8192, 256, 0, stream>>>(x, wq, bq, wk, bk, wv, bv, q, k, v);
    qk_partial_k<<<16*NSLICE, 256, 0, stream>>>(q, k, partial);
    reduce_logits_k<<<256, 256, 0, stream>>>(partial, logits);
    softmax_k<<<16, 256, 0, stream>>>(logits, att);
    attv_k<<<16*128, 256, 0, stream>>>(v, att, y);
    conv3x3_k<1><<<8192, 256, 0, stream>>>(y, wo, bo, nullptr, nullptr, nullptr, nullptr,
                                           out, nullptr, nullptr);
}

// Round 4
// 674.848 us; speedup vs baseline: 2.0623x; 2.0623x over previous
//
#include <hip/hip_runtime.h>

// Problem constants (B=2, T=64 -> N=128 images; C=O=16; H=W=128; nh=8, hc=2, D=32768)
#define NIMG 128
#define CH   16
#define HPIX 128
#define WPIX 128
#define HW   16384          // 128*128
#define TT   64             // tokens
#define QSZ  33554432       // NIMG*CH*HW floats per q/k/v buffer
#define NSLICE 32
#define SCALE_ATT 0.0055242717280199f  // 1/sqrt(32768)

typedef __attribute__((ext_vector_type(8))) short bf16x8;   // 8 bf16 = 4 VGPR (guide §3)
typedef __attribute__((ext_vector_type(4))) float f32x4;

__device__ __forceinline__ unsigned short f2bf(float x) {
    unsigned u = __float_as_uint(x);
    return (unsigned short)((u + 0x7FFFu + ((u >> 16) & 1u)) >> 16);   // RNE
}

// ---------------- NCHW fp32 -> NHWC bf16 transpose (memory-bound ~35us) ----------------
// block: n = bid>>6, rows h0..h0+1. LDS [ic][pix] fp32 -> conflict-free both phases.
__global__ __launch_bounds__(256) void nchw2nhwc_k(
    const float* __restrict__ src, unsigned short* __restrict__ dst)
{
    __shared__ float ls[16][256];
    const int bid = blockIdx.x;
    const int n = bid >> 6, h0 = (bid & 63) * 2;
    const int tid = threadIdx.x;
    const float* sp = src + (size_t)n*CH*HW + h0*WPIX + tid;   // 2 rows = 256 pix
    #pragma unroll
    for (int ic = 0; ic < 16; ++ic)
        ls[ic][tid] = sp[(size_t)ic*HW];
    __syncthreads();
    unsigned short tmp[16];
    #pragma unroll
    for (int ic = 0; ic < 16; ++ic)
        tmp[ic] = f2bf(ls[ic][tid]);
    bf16x8* d = (bf16x8*)(dst + ((size_t)n*HW + h0*WPIX)*16);
    d[tid*2]     = *(bf16x8*)&tmp[0];
    d[tid*2 + 1] = *(bf16x8*)&tmp[8];
}

// ---------------- MFMA implicit-GEMM conv 3x3 pad 1 ------------------------------------
// out[oc][pix] = W[16][K=160] * patch[K][pix], K = tap*16 + ic (tap 9 = zero pad).
// Block: 4 waves, 4 output rows x 64 cols. LDS x-tile [7 rows][66 cols][16 ic] bf16,
// row 6 zeroed (feeds tap 9); chunk swizzle half^=col[2] -> 2-way banks (free, m136).
// mfma_f32_16x16x32_bf16 frags (m89-verified): A/B lane&15=m/n, k=(lane>>4)*8+e;
// D row=(lane>>4)*4+reg (=oc), col=lane&15 (=pixel).
template<int NC>
__global__ __launch_bounds__(256, NC == 3 ? 3 : 4) void conv_mfma_k(
    const unsigned short* __restrict__ xT,   // [n][128][128][16] bf16
    const float* __restrict__ w0, const float* __restrict__ b0,
    const float* __restrict__ w1, const float* __restrict__ b1,
    const float* __restrict__ w2, const float* __restrict__ b2,
    float* __restrict__ o0, float* __restrict__ o1, float* __restrict__ o2)
{
    __shared__ unsigned short xs[7*66*16];      // 14784 B
    __shared__ unsigned short wls[NC*5*64*8];   // NC*5120 B

    const int bid = blockIdx.x;
    const int n     = bid >> 6;
    const int h0    = ((bid >> 1) & 31) * 4;
    const int w0pix = (bid & 1) * 64;
    const int tid  = threadIdx.x;
    const int lane = tid & 63, wid = tid >> 6;
    const int lanelo = lane & 15, hi = lane >> 5, ichalf = (lane >> 4) & 1;

    // stage weight fragments: wls[cv][ks][lane][e] = W[oc=lane&15][k=ks*32+(lane>>4)*8+e]
    const float* wps[3] = {w0, w1, w2};
    for (int i = tid; i < NC*2560; i += 256) {
        int e = i & 7, ln = (i >> 3) & 63, ks = (i >> 9) % 5, cv = i / 2560;
        int kk = ks*32 + (ln >> 4)*8 + e;
        float val = 0.f;
        if (kk < 144) {
            int tap = kk >> 4, ic = kk & 15;
            val = wps[cv][(ln & 15)*144 + ic*9 + tap];
        }
        wls[i] = f2bf(val);
    }

    // stage x tile: rows h0-1..h0+4 (idx 0..5), zero row idx 6; cols w0pix-1..w0pix+64
    for (int c = tid; c < 7*66*2; c += 256) {
        int half = c & 1, col = (c >> 1) % 66, row = (c >> 1) / 66;
        int gh = h0 - 1 + row, gw = w0pix - 1 + col;
        bf16x8 val = {0,0,0,0,0,0,0,0};
        if (row < 6 && (unsigned)gh < 128u && (unsigned)gw < 128u)
            val = *(const bf16x8*)(xT + (((size_t)n*128 + gh)*128 + gw)*16 + half*8);
        int sw = half ^ ((col >> 2) & 1);
        *(bf16x8*)&xs[(row*66 + col)*16 + sw*8] = val;
    }
    __syncthreads();

    // A fragments to registers (reused for 4 tiles)
    bf16x8 afr[NC][5];
    #pragma unroll
    for (int cv = 0; cv < NC; ++cv)
        #pragma unroll
        for (int ks = 0; ks < 5; ++ks)
            afr[cv][ks] = *(const bf16x8*)&wls[((cv*5 + ks)*64 + lane)*8];

    const float* bps[3] = {b0, b1, b2};
    float biasr[NC][4];
    #pragma unroll
    for (int cv = 0; cv < NC; ++cv)
        #pragma unroll
        for (int j = 0; j < 4; ++j)
            biasr[cv][j] = bps[cv][(lane >> 4)*4 + j];

    float* ops[3] = {o0, o1, o2};

    #pragma unroll
    for (int t = 0; t < 4; ++t) {
        f32x4 acc[NC];
        #pragma unroll
        for (int cv = 0; cv < NC; ++cv)
            #pragma unroll
            for (int j = 0; j < 4; ++j) acc[cv][j] = biasr[cv][j];

        #pragma unroll
        for (int ks = 0; ks < 5; ++ks) {
            int tap = 2*ks + hi;
            int r = tap / 3, cc = tap - r*3;
            int srow = (tap == 9) ? 6 : (wid + r);
            int scol = t*16 + lanelo + cc;
            int sw = ichalf ^ ((scol >> 2) & 1);
            bf16x8 bfr = *(const bf16x8*)&xs[(srow*66 + scol)*16 + sw*8];
            #pragma unroll
            for (int cv = 0; cv < NC; ++cv)
                acc[cv] = __builtin_amdgcn_mfma_f32_16x16x32_bf16(
                              afr[cv][ks], bfr, acc[cv], 0, 0, 0);
        }

        const int pix = (h0 + wid)*WPIX + w0pix + t*16 + lanelo;
        #pragma unroll
        for (int cv = 0; cv < NC; ++cv) {
            float* op = ops[cv] + ((size_t)n*16 + (lane >> 4)*4)*HW + pix;
            #pragma unroll
            for (int j = 0; j < 4; ++j)
                op[(size_t)j*HW] = acc[cv][j];
        }
    }
}

// ---------------- QK^T partial sums over d-slices (fp32, unchanged) --------------------
__global__ __launch_bounds__(256, 4) void qk_partial_k(
    const float* __restrict__ q, const float* __restrict__ k,
    float* __restrict__ partial)
{
    __shared__ float qs[64][65];
    __shared__ float ks[64][65];
    const int slice = blockIdx.x & (NSLICE-1);
    const int bh = blockIdx.x >> 5;
    const int b = bh >> 3, h = bh & 7;
    const int tid = threadIdx.x;
    const int ss = (tid & 15) * 4;
    const int tt = (tid >> 4) * 4;

    float acc[4][4];
    #pragma unroll
    for (int i = 0; i < 4; ++i)
        #pragma unroll
        for (int j = 0; j < 4; ++j) acc[i][j] = 0.f;

    for (int c = 0; c < 2; ++c) {
        for (int pc = 0; pc < 8; ++pc) {
            const int pixbase = slice*512 + pc*64;
            __syncthreads();
            for (int i = tid; i < 4096; i += 256) {
                int t = i >> 6, p = i & 63;
                int gidx = ((b*TT + t)*CH + 2*h + c)*HW + pixbase + p;
                qs[t][p] = q[gidx];
                ks[t][p] = k[gidx];
            }
            __syncthreads();
            for (int p = 0; p < 64; ++p) {
                float q4[4], k4[4];
                #pragma unroll
                for (int i = 0; i < 4; ++i) { q4[i] = qs[tt+i][p]; k4[i] = ks[ss+i][p]; }
                #pragma unroll
                for (int i = 0; i < 4; ++i)
                    #pragma unroll
                    for (int j = 0; j < 4; ++j)
                        acc[i][j] = fmaf(q4[i], k4[j], acc[i][j]);
            }
        }
    }

    float* pp = partial + (size_t)blockIdx.x * 4096;
    #pragma unroll
    for (int i = 0; i < 4; ++i)
        #pragma unroll
        for (int j = 0; j < 4; ++j)
            pp[(tt+i)*64 + (ss+j)] = acc[i][j];
}

// ---------------- reduce partials -> logits --------------------------------------------
__global__ __launch_bounds__(256) void reduce_logits_k(
    const float* __restrict__ partial, float* __restrict__ logits)
{
    int idx = blockIdx.x * 256 + threadIdx.x;
    int bh = idx >> 12, ts = idx & 4095;
    float s = 0.f;
    for (int sl = 0; sl < NSLICE; ++sl)
        s += partial[((size_t)(bh*NSLICE) + sl)*4096 + ts];
    logits[idx] = s;
}

// ---------------- causal softmax; writes att transposed att[bh][s][t] ------------------
__global__ __launch_bounds__(256) void softmax_k(
    const float* __restrict__ logits, float* __restrict__ att)
{
    const int bh = blockIdx.x;
    const int tid = threadIdx.x;
    const int t = tid >> 2, sg = tid & 3;
    float r[16];
    #pragma unroll
    for (int i = 0; i < 16; ++i) {
        int s = sg*16 + i;
        float val = logits[bh*4096 + t*64 + s] * SCALE_ATT;
        r[i] = (s <= t) ? val : -1e30f;
    }
    float m = r[0];
    #pragma unroll
    for (int i = 1; i < 16; ++i) m = fmaxf(m, r[i]);
    m = fmaxf(m, __shfl_xor(m, 1));
    m = fmaxf(m, __shfl_xor(m, 2));
    float sum = 0.f;
    #pragma unroll
    for (int i = 0; i < 16; ++i) {
        int s = sg*16 + i;
        r[i] = (s <= t) ? expf(r[i] - m) : 0.f;
        sum += r[i];
    }
    sum += __shfl_xor(sum, 1);
    sum += __shfl_xor(sum, 2);
    const float inv = 1.f / sum;
    #pragma unroll
    for (int i = 0; i < 16; ++i) {
        int s = sg*16 + i;
        att[(bh*64 + s)*64 + t] = r[i] * inv;
    }
}

// ---------------- y = att @ v (fp32, unchanged) ----------------------------------------
__global__ __launch_bounds__(256, 2) void attv_k(
    const float* __restrict__ v, const float* __restrict__ att,
    float* __restrict__ y)
{
    const int chunk = blockIdx.x & 127;
    const int bh = blockIdx.x >> 7;
    const int b = bh >> 3, h = bh & 7;
    const int d = chunk*256 + threadIdx.x;
    const int c = d >> 14, pix = d & (HW-1);
    const float* vp = v + ((size_t)(b*TT)*CH + 2*h + c)*HW + pix;
    const float* ap = att + bh*4096;
    float acc[64];
    #pragma unroll
    for (int t = 0; t < 64; ++t) acc[t] = 0.f;
    for (int s = 0; s < 64; ++s) {
        float vv = vp[(size_t)s*CH*HW];
        #pragma unroll
        for (int t = 0; t < 64; ++t)
            acc[t] = fmaf(ap[s*64 + t], vv, acc[t]);
    }
    float* yp = y + ((size_t)(b*TT)*CH + 2*h + c)*HW + pix;
    #pragma unroll
    for (int t = 0; t < 64; ++t)
        yp[(size_t)t*CH*HW] = acc[t];
}

// ---------------- launch ---------------------------------------------------------------
extern "C" void kernel_launch(void* const* d_in, const int* in_sizes, int n_in,
                              void* d_out, int out_size, void* d_ws, size_t ws_size,
                              hipStream_t stream)
{
    const float* x   = (const float*)d_in[0];
    const float* wq  = (const float*)d_in[1];
    const float* bq  = (const float*)d_in[2];
    const float* wk  = (const float*)d_in[3];
    const float* bk  = (const float*)d_in[4];
    const float* wvv = (const float*)d_in[5];
    const float* bv  = (const float*)d_in[6];
    const float* wo  = (const float*)d_in[7];
    const float* bo  = (const float*)d_in[8];
    float* out = (float*)d_out;

    float* ws = (float*)d_ws;
    float* q = ws;
    float* k = ws + (size_t)QSZ;
    float* v = ws + 2*(size_t)QSZ;
    float* shared = ws + 3*(size_t)QSZ;
    // lifetime-overlapped region (~67 MB): xT (dead after conv<3>) -> partial/logits/att
    // (dead after attv) -> yT.  Peak ws = 3*128 MB + 67 MB ~= 470 MB.
    unsigned short* xT = (unsigned short*)shared;
    float* partial = shared;
    float* logits  = shared + 2097152;
    float* att     = logits + 65536;
    unsigned short* yT = (unsigned short*)shared;
    float* y = q;   // q dead after qk_partial

    nchw2nhwc_k<<<8192, 256, 0, stream>>>(x, xT);
    conv_mfma_k<3><<<8192, 256, 0, stream>>>(xT, wq, bq, wk, bk, wvv, bv, q, k, v);
    qk_partial_k<<<16*NSLICE, 256, 0, stream>>>(q, k, partial);
    reduce_logits_k<<<256, 256, 0, stream>>>(partial, logits);
    softmax_k<<<16, 256, 0, stream>>>(logits, att);
    attv_k<<<16*128, 256, 0, stream>>>(v, att, y);
    nchw2nhwc_k<<<8192, 256, 0, stream>>>(y, yT);
    conv_mfma_k<1><<<8192, 256, 0, stream>>>(yT, wo, bo, nullptr, nullptr, nullptr,
                                             nullptr, out, nullptr, nullptr);
}

// Round 5
// 605.857 us; speedup vs baseline: 2.2971x; 1.1139x over previous
//
#include <hip/hip_runtime.h>

// B=2, T=64 -> N=128 images; C=O=16; H=W=128; nh=8, hc=2, D=32768
#define NIMG 128
#define CH   16
#define HPIX 128
#define WPIX 128
#define HW   16384
#define TT   64
#define NSLICE_QK 32                   // d-slices for qk partials (512 blocks)
#define SCALE_ATT 0.0055242717280199f  // 1/sqrt(32768)

typedef __attribute__((ext_vector_type(8))) short bf16x8;
typedef __attribute__((ext_vector_type(4))) float f32x4;
typedef __attribute__((ext_vector_type(4))) unsigned short u16x4;
typedef __attribute__((ext_vector_type(8))) unsigned short u16x8;

__device__ __forceinline__ unsigned short f2bf(float x) {
    unsigned u = __float_as_uint(x);
    return (unsigned short)((u + 0x7FFFu + ((u >> 16) & 1u)) >> 16);   // RNE
}
__device__ __forceinline__ float bf2f(unsigned short u) {
    return __uint_as_float(((unsigned)u) << 16);
}

// ---------------- NCHW fp32 -> NHWC bf16 transpose (x only now) ------------------------
__global__ __launch_bounds__(256) void nchw2nhwc_k(
    const float* __restrict__ src, unsigned short* __restrict__ dst)
{
    __shared__ float ls[16][256];
    const int bid = blockIdx.x;
    const int n = bid >> 6, h0 = (bid & 63) * 2;
    const int tid = threadIdx.x;
    const float* sp = src + (size_t)n*CH*HW + h0*WPIX + tid;
    #pragma unroll
    for (int ic = 0; ic < 16; ++ic)
        ls[ic][tid] = sp[(size_t)ic*HW];
    __syncthreads();
    unsigned short tmp[16];
    #pragma unroll
    for (int ic = 0; ic < 16; ++ic)
        tmp[ic] = f2bf(ls[ic][tid]);
    u16x8* d = (u16x8*)(dst + ((size_t)n*HW + h0*WPIX)*16);
    d[tid*2]     = *(u16x8*)&tmp[0];
    d[tid*2 + 1] = *(u16x8*)&tmp[8];
}

// ---------------- MFMA implicit-GEMM conv 3x3 pad 1 ------------------------------------
// NC=3: outputs q,k head-major bf16 [b][h][t][c*HW+pix]; v NHWC bf16 [n][pix][16].
// NC=1: output fp32 NCHW (harness layout).
// D-frag (m89): row(=oc) = (lane>>4)*4+reg, col(=pix) = lane&15.
template<int NC>
__global__ __launch_bounds__(256, NC == 3 ? 3 : 4) void conv_mfma_k(
    const unsigned short* __restrict__ xT,   // [n][128][128][16] bf16
    const float* __restrict__ w0, const float* __restrict__ b0,
    const float* __restrict__ w1, const float* __restrict__ b1,
    const float* __restrict__ w2, const float* __restrict__ b2,
    unsigned short* __restrict__ oq, unsigned short* __restrict__ ok,
    unsigned short* __restrict__ ov, float* __restrict__ ofp)
{
    __shared__ unsigned short xs[7*66*16];
    __shared__ unsigned short wls[NC*5*64*8];

    const int bid = blockIdx.x;
    const int n     = bid >> 6;
    const int h0    = ((bid >> 1) & 31) * 4;
    const int w0pix = (bid & 1) * 64;
    const int tid  = threadIdx.x;
    const int lane = tid & 63, wid = tid >> 6;
    const int lanelo = lane & 15, hi = lane >> 5, ichalf = (lane >> 4) & 1;
    const int quad = lane >> 4;

    const float* wps[3] = {w0, w1, w2};
    for (int i = tid; i < NC*2560; i += 256) {
        int e = i & 7, ln = (i >> 3) & 63, ks = (i >> 9) % 5, cv = i / 2560;
        int kk = ks*32 + (ln >> 4)*8 + e;
        float val = 0.f;
        if (kk < 144) {
            int tap = kk >> 4, ic = kk & 15;
            val = wps[cv][(ln & 15)*144 + ic*9 + tap];
        }
        wls[i] = f2bf(val);
    }

    for (int c = tid; c < 7*66*2; c += 256) {
        int half = c & 1, col = (c >> 1) % 66, row = (c >> 1) / 66;
        int gh = h0 - 1 + row, gw = w0pix - 1 + col;
        u16x8 val = {0,0,0,0,0,0,0,0};
        if (row < 6 && (unsigned)gh < 128u && (unsigned)gw < 128u)
            val = *(const u16x8*)(xT + (((size_t)n*128 + gh)*128 + gw)*16 + half*8);
        int sw = half ^ ((col >> 2) & 1);
        *(u16x8*)&xs[(row*66 + col)*16 + sw*8] = val;
    }
    __syncthreads();

    bf16x8 afr[NC][5];
    #pragma unroll
    for (int cv = 0; cv < NC; ++cv)
        #pragma unroll
        for (int ks = 0; ks < 5; ++ks)
            afr[cv][ks] = *(const bf16x8*)&wls[((cv*5 + ks)*64 + lane)*8];

    const float* bps[3] = {b0, b1, b2};
    float biasr[NC][4];
    #pragma unroll
    for (int cv = 0; cv < NC; ++cv)
        #pragma unroll
        for (int j = 0; j < 4; ++j)
            biasr[cv][j] = bps[cv][quad*4 + j];

    const int b = n >> 6, tok = n & 63;

    #pragma unroll
    for (int t = 0; t < 4; ++t) {
        f32x4 acc[NC];
        #pragma unroll
        for (int cv = 0; cv < NC; ++cv)
            #pragma unroll
            for (int j = 0; j < 4; ++j) acc[cv][j] = biasr[cv][j];

        #pragma unroll
        for (int ks = 0; ks < 5; ++ks) {
            int tap = 2*ks + hi;
            int r = tap / 3, cc = tap - r*3;
            int srow = (tap == 9) ? 6 : (wid + r);
            int scol = t*16 + lanelo + cc;
            int sw = ichalf ^ ((scol >> 2) & 1);
            bf16x8 bfr = *(const bf16x8*)&xs[(srow*66 + scol)*16 + sw*8];
            #pragma unroll
            for (int cv = 0; cv < NC; ++cv)
                acc[cv] = __builtin_amdgcn_mfma_f32_16x16x32_bf16(
                              afr[cv][ks], bfr, acc[cv], 0, 0, 0);
        }

        const int pix = (h0 + wid)*WPIX + w0pix + t*16 + lanelo;
        if constexpr (NC == 3) {
            // q,k head-major: oc=quad*4+j -> h=oc>>1, c=oc&1
            #pragma unroll
            for (int j = 0; j < 4; ++j) {
                int oc = quad*4 + j;
                size_t off = ((size_t)((b*8 + (oc >> 1))*64 + tok))*32768
                           + (size_t)(oc & 1)*HW + pix;
                oq[off] = f2bf(acc[0][j]);
                ok[off] = f2bf(acc[1][j]);
            }
            // v NHWC: 4 consecutive oc at this pixel -> one 8B store
            u16x4 pk;
            #pragma unroll
            for (int j = 0; j < 4; ++j) pk[j] = f2bf(acc[2][j]);
            *(u16x4*)(ov + ((size_t)n*HW + pix)*16 + quad*4) = pk;
        } else {
            float* op = ofp + ((size_t)n*16 + quad*4)*HW + pix;
            #pragma unroll
            for (int j = 0; j < 4; ++j)
                op[(size_t)j*HW] = acc[0][j];
        }
    }
}

// ---------------- QK^T partials, MFMA bf16 ---------------------------------------------
// grid = 16 bh * NSLICE_QK. Block: 64x64 scores over d-slice of 1024.
// LDS tiles [64 rows][64 d] bf16, 16B-chunk swizzle: chunk = row*8+dp -> dp^(row&7).
__global__ __launch_bounds__(256, 4) void qk_mfma_k(
    const unsigned short* __restrict__ qA, const unsigned short* __restrict__ kA,
    float* __restrict__ partial)
{
    __shared__ unsigned short qs[64*64];
    __shared__ unsigned short ks[64*64];
    const int slice = blockIdx.x & (NSLICE_QK-1);
    const int bh = blockIdx.x >> 5;
    const int tid = threadIdx.x;
    const int lane = tid & 63;
    const int grp = lane >> 4, lanelo = lane & 15;
    const size_t base = (size_t)bh*64*32768 + (size_t)slice*1024;

    f32x4 acc[4][4];
    #pragma unroll
    for (int i = 0; i < 4; ++i)
        #pragma unroll
        for (int j = 0; j < 4; ++j)
            #pragma unroll
            for (int e = 0; e < 4; ++e) acc[i][j][e] = 0.f;

    for (int ch = 0; ch < 16; ++ch) {        // 16 chunks of 64 d
        __syncthreads();
        for (int i = tid; i < 512; i += 256) {
            int t = i >> 3, dp = i & 7;
            int sw = dp ^ (t & 7);
            const size_t g = base + (size_t)t*32768 + ch*64 + dp*8;
            *(u16x8*)&qs[t*64 + sw*8] = *(const u16x8*)(qA + g);
            *(u16x8*)&ks[t*64 + sw*8] = *(const u16x8*)(kA + g);
        }
        __syncthreads();
        #pragma unroll
        for (int kh = 0; kh < 2; ++kh) {
            const int dchunk = kh*4 + grp;
            bf16x8 af[4], bf[4];
            #pragma unroll
            for (int ti = 0; ti < 4; ++ti) {
                int t = ti*16 + lanelo;
                int sw = dchunk ^ (t & 7);
                af[ti] = *(const bf16x8*)&qs[t*64 + sw*8];
                bf[ti] = *(const bf16x8*)&ks[t*64 + sw*8];
            }
            #pragma unroll
            for (int ti = 0; ti < 4; ++ti)
                #pragma unroll
                for (int si = 0; si < 4; ++si)
                    acc[ti][si] = __builtin_amdgcn_mfma_f32_16x16x32_bf16(
                                      af[ti], bf[si], acc[ti][si], 0, 0, 0);
        }
    }

    float* pp = partial + (size_t)blockIdx.x * 4096;   // [bh][slice][t][s]
    #pragma unroll
    for (int ti = 0; ti < 4; ++ti)
        #pragma unroll
        for (int si = 0; si < 4; ++si)
            #pragma unroll
            for (int j = 0; j < 4; ++j) {
                int row = ti*16 + grp*4 + j;
                int col = si*16 + lanelo;
                pp[row*64 + col] = acc[ti][si][j];
            }
}

// ---------------- reduce partials -> logits --------------------------------------------
__global__ __launch_bounds__(256) void reduce_logits_k(
    const float* __restrict__ partial, float* __restrict__ logits)
{
    int idx = blockIdx.x * 256 + threadIdx.x;   // [0, 16*4096)
    int bh = idx >> 12, ts = idx & 4095;
    float s = 0.f;
    for (int sl = 0; sl < NSLICE_QK; ++sl)
        s += partial[((size_t)(bh*NSLICE_QK) + sl)*4096 + ts];
    logits[idx] = s;
}

// ---------------- causal softmax -> bf16 att[bh][s][t] ---------------------------------
__global__ __launch_bounds__(256) void softmax_k(
    const float* __restrict__ logits, unsigned short* __restrict__ att)
{
    const int bh = blockIdx.x;
    const int tid = threadIdx.x;
    const int t = tid >> 2, sg = tid & 3;
    float r[16];
    #pragma unroll
    for (int i = 0; i < 16; ++i) {
        int s = sg*16 + i;
        float val = logits[bh*4096 + t*64 + s] * SCALE_ATT;
        r[i] = (s <= t) ? val : -1e30f;
    }
    float m = r[0];
    #pragma unroll
    for (int i = 1; i < 16; ++i) m = fmaxf(m, r[i]);
    m = fmaxf(m, __shfl_xor(m, 1));
    m = fmaxf(m, __shfl_xor(m, 2));
    float sum = 0.f;
    #pragma unroll
    for (int i = 0; i < 16; ++i) {
        int s = sg*16 + i;
        r[i] = (s <= t) ? expf(r[i] - m) : 0.f;
        sum += r[i];
    }
    sum += __shfl_xor(sum, 1);
    sum += __shfl_xor(sum, 2);
    const float inv = 1.f / sum;
    #pragma unroll
    for (int i = 0; i < 16; ++i) {
        int s = sg*16 + i;
        att[(bh*64 + s)*64 + t] = f2bf(r[i] * inv);
    }
}

// ---------------- y = att @ v, NHWC bf16 in/out ----------------------------------------
// grid = 2b * 1024 pix-tiles(16). Thread = (pix, oc); all 8 heads' att staged in 64KB LDS
// [h][s][t] bf16, 16B-chunk swizzled (chunk ^= h) -> conflict-free b128 reads (broadcast).
__global__ __launch_bounds__(256, 2) void attv_k(
    const unsigned short* __restrict__ vT, const unsigned short* __restrict__ att,
    unsigned short* __restrict__ yT)
{
    __shared__ unsigned short att_s[32768];   // 64 KB exactly
    const int blk = blockIdx.x;
    const int b = blk >> 10, pixbase = (blk & 1023) * 16;
    const int tid = threadIdx.x;

    const unsigned short* src = att + (size_t)b*8*4096;
    for (int c = tid; c < 4096; c += 256) {            // 4096 16B-chunks
        int cs = c ^ ((c >> 9) & 7);
        *(u16x8*)&att_s[cs*8] = *(const u16x8*)(src + c*8);
    }
    __syncthreads();

    const int po = tid >> 4, oc = tid & 15, hh = oc >> 1;
    const int pix = pixbase + po;
    const unsigned short* vp = vT + ((size_t)(b*64)*HW + pix)*16 + oc;

    float acc[64];
    #pragma unroll
    for (int t = 0; t < 64; ++t) acc[t] = 0.f;

    for (int s = 0; s < 64; ++s) {
        float vv = bf2f(vp[(size_t)s*HW*16]);
        const int crow = hh*512 + s*8;
        #pragma unroll
        for (int t0 = 0; t0 < 64; t0 += 8) {
            int c = crow + (t0 >> 3);
            u16x8 a8 = *(const u16x8*)&att_s[(c ^ hh)*8];
            #pragma unroll
            for (int j = 0; j < 8; ++j)
                acc[t0 + j] = fmaf(bf2f(a8[j]), vv, acc[t0 + j]);
        }
    }

    #pragma unroll
    for (int t = 0; t < 64; ++t)
        yT[(((size_t)(b*64 + t))*HW + pix)*16 + oc] = f2bf(acc[t]);
}

// ---------------- launch ---------------------------------------------------------------
extern "C" void kernel_launch(void* const* d_in, const int* in_sizes, int n_in,
                              void* d_out, int out_size, void* d_ws, size_t ws_size,
                              hipStream_t stream)
{
    const float* x   = (const float*)d_in[0];
    const float* wq  = (const float*)d_in[1];
    const float* bq  = (const float*)d_in[2];
    const float* wk  = (const float*)d_in[3];
    const float* bk  = (const float*)d_in[4];
    const float* wvv = (const float*)d_in[5];
    const float* bv  = (const float*)d_in[6];
    const float* wo  = (const float*)d_in[7];
    const float* bo  = (const float*)d_in[8];
    float* out = (float*)d_out;

    unsigned short* xT = (unsigned short*)d_ws;        // 32Mi shorts = 64MB each
    unsigned short* qA = xT + 33554432;
    unsigned short* kA = qA + 33554432;
    unsigned short* vT = kA + 33554432;
    unsigned short* yT = vT + 33554432;
    float* partial = (float*)(yT + 33554432);          // 16*32*4096 f32 = 8MB
    float* logits  = partial + 16*NSLICE_QK*4096;      // 256KB
    unsigned short* att_bf = (unsigned short*)(logits + 65536);   // 128KB

    nchw2nhwc_k<<<8192, 256, 0, stream>>>(x, xT);
    conv_mfma_k<3><<<8192, 256, 0, stream>>>(xT, wq, bq, wk, bk, wvv, bv,
                                             qA, kA, vT, nullptr);
    qk_mfma_k<<<16*NSLICE_QK, 256, 0, stream>>>(qA, kA, partial);
    reduce_logits_k<<<256, 256, 0, stream>>>(partial, logits);
    softmax_k<<<16, 256, 0, stream>>>(logits, att_bf);
    attv_k<<<2048, 256, 0, stream>>>(vT, att_bf, yT);
    conv_mfma_k<1><<<8192, 256, 0, stream>>>(yT, wo, bo, nullptr, nullptr, nullptr,
                                             nullptr, nullptr, nullptr, nullptr, out);
}

// Round 7
// 486.104 us; speedup vs baseline: 2.8630x; 1.2464x over previous
//
#include <hip/hip_runtime.h>

// B=2, T=64 -> N=128 images; C=O=16; H=W=128; nh=8, hc=2, D=32768
// Layouts: q/k/v/y head-split bf16 [b][h][t|s][d] with d = pix*2 + c  (c = oc&1)
#define NIMG 128
#define CH   16
#define HPIX 128
#define WPIX 128
#define HW   16384
#define TT   64
#define NSLICE_QK 32
#define SCALE_ATT 0.0055242717280199f  // 1/sqrt(32768)

typedef __attribute__((ext_vector_type(8))) short bf16x8;
typedef __attribute__((ext_vector_type(4))) float f32x4;
typedef __attribute__((ext_vector_type(2))) unsigned short u16x2;
typedef __attribute__((ext_vector_type(8))) unsigned short u16x8;

__device__ __forceinline__ unsigned short f2bf(float x) {
    unsigned u = __float_as_uint(x);
    return (unsigned short)((u + 0x7FFFu + ((u >> 16) & 1u)) >> 16);   // RNE
}
__device__ __forceinline__ float bf2f(unsigned short u) {
    return __uint_as_float(((unsigned)u) << 16);
}

// ---------------- NCHW fp32 -> NHWC bf16 transpose (x only) ----------------------------
__global__ __launch_bounds__(256) void nchw2nhwc_k(
    const float* __restrict__ src, unsigned short* __restrict__ dst)
{
    __shared__ float ls[16][256];
    const int bid = blockIdx.x;
    const int n = bid >> 6, h0 = (bid & 63) * 2;
    const int tid = threadIdx.x;
    const float* sp = src + (size_t)n*CH*HW + h0*WPIX + tid;
    #pragma unroll
    for (int ic = 0; ic < 16; ++ic)
        ls[ic][tid] = sp[(size_t)ic*HW];
    __syncthreads();
    unsigned short tmp[16];
    #pragma unroll
    for (int ic = 0; ic < 16; ++ic)
        tmp[ic] = f2bf(ls[ic][tid]);
    u16x8* d = (u16x8*)(dst + ((size_t)n*HW + h0*WPIX)*16);
    d[tid*2]     = *(u16x8*)&tmp[0];
    d[tid*2 + 1] = *(u16x8*)&tmp[8];
}

// ---------------- MFMA implicit-GEMM conv 3x3 pad 1 ------------------------------------
// NC=3: input xT NHWC bf16; outputs q,k,v head-split bf16 (u16x2 packed stores).
// NC=1: input yH head-split bf16; output fp32 NCHW (harness layout).
template<int NC>
__global__ __launch_bounds__(256, NC == 3 ? 3 : 4) void conv_mfma_k(
    const unsigned short* __restrict__ xin,
    const float* __restrict__ w0, const float* __restrict__ b0,
    const float* __restrict__ w1, const float* __restrict__ b1,
    const float* __restrict__ w2, const float* __restrict__ b2,
    unsigned short* __restrict__ oq, unsigned short* __restrict__ ok,
    unsigned short* __restrict__ ov, float* __restrict__ ofp)
{
    __shared__ unsigned short xs[7*66*16];
    __shared__ unsigned short wls[NC*5*64*8];

    const int bid = blockIdx.x;
    const int n     = bid >> 6;
    const int h0    = ((bid >> 1) & 31) * 4;
    const int w0pix = (bid & 1) * 64;
    const int tid  = threadIdx.x;
    const int lane = tid & 63, wid = tid >> 6;
    const int lanelo = lane & 15, hi = lane >> 5, ichalf = (lane >> 4) & 1;
    const int quad = lane >> 4;
    const int b = n >> 6, tok = n & 63;

    const float* wps[3] = {w0, w1, w2};
    for (int i = tid; i < NC*2560; i += 256) {
        int e = i & 7, ln = (i >> 3) & 63, ks = (i >> 9) % 5, cv = i / 2560;
        int kk = ks*32 + (ln >> 4)*8 + e;
        float val = 0.f;
        if (kk < 144) {
            int tap = kk >> 4, ic = kk & 15;
            val = wps[cv][(ln & 15)*144 + ic*9 + tap];
        }
        wls[i] = f2bf(val);
    }

    if constexpr (NC == 3) {
        // stage from NHWC xT: u16x8 chunks
        for (int c = tid; c < 7*66*2; c += 256) {
            int half = c & 1, col = (c >> 1) % 66, row = (c >> 1) / 66;
            int gh = h0 - 1 + row, gw = w0pix - 1 + col;
            u16x8 val = {0,0,0,0,0,0,0,0};
            if (row < 6 && (unsigned)gh < 128u && (unsigned)gw < 128u)
                val = *(const u16x8*)(xin + (((size_t)n*128 + gh)*128 + gw)*16 + half*8);
            int sw = half ^ ((col >> 2) & 1);
            *(u16x8*)&xs[(row*66 + col)*16 + sw*8] = val;
        }
    } else {
        // stage from head-split yH [b][h][tok][pix*2+c]: u16x2 per (pos, h)
        const size_t tbase = ((size_t)(b*8)*64 + tok)*32768;
        for (int i = tid; i < 7*8*66; i += 256) {
            int col = i % 66;
            int rh = i / 66;
            int hh = rh & 7, row = rh >> 3;
            int gh = h0 - 1 + row, gw = w0pix - 1 + col;
            u16x2 val = {0, 0};
            if (row < 6 && (unsigned)gh < 128u && (unsigned)gw < 128u)
                val = *(const u16x2*)(xin + tbase + (size_t)hh*64*32768
                                      + ((size_t)gh*128 + gw)*2);
            int sw = (hh >> 2) ^ ((col >> 2) & 1);
            *(u16x2*)&xs[(row*66 + col)*16 + sw*8 + (hh & 3)*2] = val;
        }
    }
    __syncthreads();

    bf16x8 afr[NC][5];
    #pragma unroll
    for (int cv = 0; cv < NC; ++cv)
        #pragma unroll
        for (int ks = 0; ks < 5; ++ks)
            afr[cv][ks] = *(const bf16x8*)&wls[((cv*5 + ks)*64 + lane)*8];

    const float* bps[3] = {b0, b1, b2};
    float biasr[NC][4];
    #pragma unroll
    for (int cv = 0; cv < NC; ++cv)
        #pragma unroll
        for (int j = 0; j < 4; ++j)
            biasr[cv][j] = bps[cv][quad*4 + j];

    #pragma unroll
    for (int t = 0; t < 4; ++t) {
        f32x4 acc[NC];
        #pragma unroll
        for (int cv = 0; cv < NC; ++cv)
            #pragma unroll
            for (int j = 0; j < 4; ++j) acc[cv][j] = biasr[cv][j];

        #pragma unroll
        for (int ks = 0; ks < 5; ++ks) {
            int tap = 2*ks + hi;
            int r = tap / 3, cc = tap - r*3;
            int srow = (tap == 9) ? 6 : (wid + r);
            int scol = t*16 + lanelo + cc;
            int sw = ichalf ^ ((scol >> 2) & 1);
            bf16x8 bfr = *(const bf16x8*)&xs[(srow*66 + scol)*16 + sw*8];
            #pragma unroll
            for (int cv = 0; cv < NC; ++cv)
                acc[cv] = __builtin_amdgcn_mfma_f32_16x16x32_bf16(
                              afr[cv][ks], bfr, acc[cv], 0, 0, 0);
        }

        const int pix = (h0 + wid)*WPIX + w0pix + t*16 + lanelo;
        if constexpr (NC == 3) {
            // oc = quad*4 + j -> h = oc>>1, c = oc&1; j-pairs share h, c = 0,1 packed
            #pragma unroll
            for (int jp = 0; jp < 2; ++jp) {
                int hh = quad*2 + jp;
                size_t off = ((size_t)((b*8 + hh)*64 + tok))*32768 + (size_t)pix*2;
                u16x2 pq, pk, pv;
                pq[0] = f2bf(acc[0][jp*2]); pq[1] = f2bf(acc[0][jp*2+1]);
                pk[0] = f2bf(acc[1][jp*2]); pk[1] = f2bf(acc[1][jp*2+1]);
                pv[0] = f2bf(acc[2][jp*2]); pv[1] = f2bf(acc[2][jp*2+1]);
                *(u16x2*)(oq + off) = pq;
                *(u16x2*)(ok + off) = pk;
                *(u16x2*)(ov + off) = pv;
            }
        } else {
            float* op = ofp + ((size_t)n*16 + quad*4)*HW + pix;
            #pragma unroll
            for (int j = 0; j < 4; ++j)
                op[(size_t)j*HW] = acc[0][j];
        }
    }
}

// ---------------- QK^T partials, MFMA bf16 (layout-invariant over d) -------------------
__global__ __launch_bounds__(256, 4) void qk_mfma_k(
    const unsigned short* __restrict__ qA, const unsigned short* __restrict__ kA,
    float* __restrict__ partial)
{
    __shared__ unsigned short qs[64*64];
    __shared__ unsigned short ks[64*64];
    const int slice = blockIdx.x & (NSLICE_QK-1);
    const int bh = blockIdx.x >> 5;
    const int tid = threadIdx.x;
    const int lane = tid & 63;
    const int grp = lane >> 4, lanelo = lane & 15;
    const size_t base = (size_t)bh*64*32768 + (size_t)slice*1024;

    f32x4 acc[4][4];
    #pragma unroll
    for (int i = 0; i < 4; ++i)
        #pragma unroll
        for (int j = 0; j < 4; ++j)
            #pragma unroll
            for (int e = 0; e < 4; ++e) acc[i][j][e] = 0.f;

    for (int ch = 0; ch < 16; ++ch) {
        __syncthreads();
        for (int i = tid; i < 512; i += 256) {
            int t = i >> 3, dp = i & 7;
            int sw = dp ^ (t & 7);
            const size_t g = base + (size_t)t*32768 + ch*64 + dp*8;
            *(u16x8*)&qs[t*64 + sw*8] = *(const u16x8*)(qA + g);
            *(u16x8*)&ks[t*64 + sw*8] = *(const u16x8*)(kA + g);
        }
        __syncthreads();
        #pragma unroll
        for (int kh = 0; kh < 2; ++kh) {
            const int dchunk = kh*4 + grp;
            bf16x8 af[4], bf[4];
            #pragma unroll
            for (int ti = 0; ti < 4; ++ti) {
                int t = ti*16 + lanelo;
                int sw = dchunk ^ (t & 7);
                af[ti] = *(const bf16x8*)&qs[t*64 + sw*8];
                bf[ti] = *(const bf16x8*)&ks[t*64 + sw*8];
            }
            #pragma unroll
            for (int ti = 0; ti < 4; ++ti)
                #pragma unroll
                for (int si = 0; si < 4; ++si)
                    acc[ti][si] = __builtin_amdgcn_mfma_f32_16x16x32_bf16(
                                      af[ti], bf[si], acc[ti][si], 0, 0, 0);
        }
    }

    float* pp = partial + (size_t)blockIdx.x * 4096;   // [bh][slice][t][s]
    #pragma unroll
    for (int ti = 0; ti < 4; ++ti)
        #pragma unroll
        for (int si = 0; si < 4; ++si)
            #pragma unroll
            for (int j = 0; j < 4; ++j) {
                int row = ti*16 + grp*4 + j;
                int col = si*16 + lanelo;
                pp[row*64 + col] = acc[ti][si][j];
            }
}

// ---------------- reduce partials -> logits --------------------------------------------
__global__ __launch_bounds__(256) void reduce_logits_k(
    const float* __restrict__ partial, float* __restrict__ logits)
{
    int idx = blockIdx.x * 256 + threadIdx.x;
    int bh = idx >> 12, ts = idx & 4095;
    float s = 0.f;
    for (int sl = 0; sl < NSLICE_QK; ++sl)
        s += partial[((size_t)(bh*NSLICE_QK) + sl)*4096 + ts];
    logits[idx] = s;
}

// ---------------- causal softmax -> bf16 att[bh][t][s] (natural, for MFMA A-frags) -----
__global__ __launch_bounds__(256) void softmax_k(
    const float* __restrict__ logits, unsigned short* __restrict__ att)
{
    const int bh = blockIdx.x;
    const int tid = threadIdx.x;
    const int t = tid >> 2, sg = tid & 3;
    float r[16];
    #pragma unroll
    for (int i = 0; i < 16; ++i) {
        int s = sg*16 + i;
        float val = logits[bh*4096 + t*64 + s] * SCALE_ATT;
        r[i] = (s <= t) ? val : -1e30f;
    }
    float m = r[0];
    #pragma unroll
    for (int i = 1; i < 16; ++i) m = fmaxf(m, r[i]);
    m = fmaxf(m, __shfl_xor(m, 1));
    m = fmaxf(m, __shfl_xor(m, 2));
    float sum = 0.f;
    #pragma unroll
    for (int i = 0; i < 16; ++i) {
        int s = sg*16 + i;
        r[i] = (s <= t) ? expf(r[i] - m) : 0.f;
        sum += r[i];
    }
    sum += __shfl_xor(sum, 1);
    sum += __shfl_xor(sum, 2);
    const float inv = 1.f / sum;
    #pragma unroll
    for (int i = 0; i < 16; ++i) {
        int s = sg*16 + i;
        att[bh*4096 + t*64 + s] = f2bf(r[i] * inv);
    }
}

// ---------------- y = att @ v via MFMA --------------------------------------------------
// grid = 16 bh * 128 pix-tiles. Per block: M=64(t) x N=256(d) x K=64(s).
// A = att[t][s] LDS 8KB, chunk^=(t&7) swizzle; B = v staged TRANSPOSED vs[d][s] 32KB,
// chunk^=(d&7) swizzle -> both b128 fragment reads conflict-free (derivation in notes).
__global__ __launch_bounds__(256, 3) void attv_mfma_k(
    const unsigned short* __restrict__ vH,   // [bh][s][d]
    const unsigned short* __restrict__ att,  // [bh][t][s]
    unsigned short* __restrict__ yH)         // [bh][t][d]
{
    __shared__ unsigned short vs[256*64];    // [d_local][s] swizzled, 32 KB
    __shared__ unsigned short as[64*64];     // [t][s] swizzled, 8 KB

    const int blk = blockIdx.x;
    const int pt = blk & 127;
    const int bh = blk >> 7;
    const int tid = threadIdx.x;
    const int lane = tid & 63, wid = tid >> 6;
    const int grp = lane >> 4, lanelo = lane & 15;

    const size_t vbase = (size_t)bh*64*32768 + (size_t)pt*256;

    // stage v transposed: i = dc*64 + s; per wave lanes -> s=0..63 (L2-friendly stride)
    #pragma unroll
    for (int j = 0; j < 8; ++j) {
        int i = tid + j*256;
        int s = i & 63, dc = i >> 6;
        u16x8 val = *(const u16x8*)(vH + vbase + (size_t)s*32768 + dc*8);
        #pragma unroll
        for (int e = 0; e < 8; ++e) {
            int d = dc*8 + e;
            int cs = (s >> 3) ^ (d & 7);
            vs[d*64 + cs*8 + (s & 7)] = val[e];
        }
    }
    // stage att: 512 u16x8 chunks
    #pragma unroll
    for (int j = 0; j < 2; ++j) {
        int i = tid + j*256;
        int t = i >> 3, ch = i & 7;
        int cs = ch ^ (t & 7);
        *(u16x8*)&as[t*64 + cs*8] =
            *(const u16x8*)(att + (size_t)bh*4096 + t*64 + ch*8);
    }
    __syncthreads();

    // A fragments: af[mi][ki], t = mi*16+lanelo, s-chunk = ki*4+grp
    bf16x8 af[4][2];
    #pragma unroll
    for (int mi = 0; mi < 4; ++mi)
        #pragma unroll
        for (int ki = 0; ki < 2; ++ki) {
            int t = mi*16 + lanelo;
            int cs = (ki*4 + grp) ^ (t & 7);
            af[mi][ki] = *(const bf16x8*)&as[t*64 + cs*8];
        }

    f32x4 acc[4][4];   // [mi][ni]
    #pragma unroll
    for (int mi = 0; mi < 4; ++mi)
        #pragma unroll
        for (int ni = 0; ni < 4; ++ni)
            #pragma unroll
            for (int e = 0; e < 4; ++e) acc[mi][ni][e] = 0.f;

    #pragma unroll
    for (int ki = 0; ki < 2; ++ki)
        #pragma unroll
        for (int ni = 0; ni < 4; ++ni) {
            int d = wid*64 + ni*16 + lanelo;
            int cs = (ki*4 + grp) ^ (d & 7);
            bf16x8 bf = *(const bf16x8*)&vs[d*64 + cs*8];
            #pragma unroll
            for (int mi = 0; mi < 4; ++mi)
                acc[mi][ni] = __builtin_amdgcn_mfma_f32_16x16x32_bf16(
                                  af[mi][ki], bf, acc[mi][ni], 0, 0, 0);
        }

    // store: t = mi*16 + grp*4 + j, d = wid*64 + ni*16 + lanelo -> 32B runs per group
    #pragma unroll
    for (int mi = 0; mi < 4; ++mi)
        #pragma unroll
        for (int ni = 0; ni < 4; ++ni) {
            int t = mi*16 + grp*4;
            int d = wid*64 + ni*16 + lanelo;
            #pragma unroll
            for (int j = 0; j < 4; ++j)
                yH[(size_t)bh*64*32768 + (size_t)(t + j)*32768 + pt*256 + d]
                    = f2bf(acc[mi][ni][j]);
        }
}

// ---------------- launch ---------------------------------------------------------------
extern "C" void kernel_launch(void* const* d_in, const int* in_sizes, int n_in,
                              void* d_out, int out_size, void* d_ws, size_t ws_size,
                              hipStream_t stream)
{
    const float* x   = (const float*)d_in[0];
    const float* wq  = (const float*)d_in[1];
    const float* bq  = (const float*)d_in[2];
    const float* wk  = (const float*)d_in[3];
    const float* bk  = (const float*)d_in[4];
    const float* wvv = (const float*)d_in[5];
    const float* bv  = (const float*)d_in[6];
    const float* wo  = (const float*)d_in[7];
    const float* bo  = (const float*)d_in[8];
    float* out = (float*)d_out;

    unsigned short* xT = (unsigned short*)d_ws;        // 64 MB each
    unsigned short* qA = xT + 33554432;
    unsigned short* kA = qA + 33554432;
    unsigned short* vH = kA + 33554432;
    unsigned short* yH = vH + 33554432;
    float* partial = (float*)(yH + 33554432);          // 8 MB
    float* logits  = partial + 16*NSLICE_QK*4096;      // 256 KB
    unsigned short* att_bf = (unsigned short*)(logits + 65536);   // 128 KB

    nchw2nhwc_k<<<8192, 256, 0, stream>>>(x, xT);
    conv_mfma_k<3><<<8192, 256, 0, stream>>>(xT, wq, bq, wk, bk, wvv, bv,
                                             qA, kA, vH, nullptr);
    qk_mfma_k<<<16*NSLICE_QK, 256, 0, stream>>>(qA, kA, partial);
    reduce_logits_k<<<256, 256, 0, stream>>>(partial, logits);
    softmax_k<<<16, 256, 0, stream>>>(logits, att_bf);
    attv_mfma_k<<<2048, 256, 0, stream>>>(vH, att_bf, yH);
    conv_mfma_k<1><<<8192, 256, 0, stream>>>(yH, wo, bo, nullptr, nullptr, nullptr,
                                             nullptr, nullptr, nullptr, nullptr, out);
}

// Round 8
// 426.886 us; speedup vs baseline: 3.2602x; 1.1387x over previous
//
#include <hip/hip_runtime.h>

// B=2, T=64 -> N=128 images; C=O=16; H=W=128; nh=8, hc=2, D=32768
// Layouts: q/k/v/y head-split bf16 [b][h][t|s][d] with d = pix*2 + c  (c = oc&1)
#define NIMG 128
#define CH   16
#define HPIX 128
#define WPIX 128
#define HW   16384
#define TT   64
#define NSLICE_QK 64
#define SCALE_ATT 0.0055242717280199f  // 1/sqrt(32768)

typedef __attribute__((ext_vector_type(8))) short bf16x8;
typedef __attribute__((ext_vector_type(4))) float f32x4;
typedef __attribute__((ext_vector_type(2))) unsigned short u16x2;
typedef __attribute__((ext_vector_type(8))) unsigned short u16x8;

__device__ __forceinline__ unsigned short f2bf(float x) {
    unsigned u = __float_as_uint(x);
    return (unsigned short)((u + 0x7FFFu + ((u >> 16) & 1u)) >> 16);   // RNE
}
__device__ __forceinline__ float bf2f(unsigned short u) {
    return __uint_as_float(((unsigned)u) << 16);
}

// ---------------- weight prepack: MFMA A-fragment layout, once ------------------------
// wpk[cv][ks][lane][e] = W_cv[oc=lane&15][k=ks*32+(lane>>4)*8+e], k>=144 -> 0.
// cv: 0=wq 1=wk 2=wv 3=wo. 4*2560 = 10240 elements total.
__global__ __launch_bounds__(256) void prepack_w_k(
    const float* __restrict__ wq, const float* __restrict__ wk,
    const float* __restrict__ wv, const float* __restrict__ wo,
    unsigned short* __restrict__ wpk)
{
    const float* wps[4] = {wq, wk, wv, wo};
    int i = blockIdx.x*256 + threadIdx.x;
    if (i >= 4*2560) return;
    int cv = i / 2560, r = i - cv*2560;
    int ks = r >> 9, ln = (r >> 3) & 63, e = r & 7;
    int kk = ks*32 + (ln >> 4)*8 + e;
    float val = 0.f;
    if (kk < 144) {
        int tap = kk >> 4, ic = kk & 15;
        val = wps[cv][(ln & 15)*144 + ic*9 + tap];
    }
    wpk[i] = f2bf(val);
}

// ---------------- NCHW fp32 -> NHWC bf16 transpose (x only) ----------------------------
__global__ __launch_bounds__(256) void nchw2nhwc_k(
    const float* __restrict__ src, unsigned short* __restrict__ dst)
{
    __shared__ float ls[16][256];
    const int bid = blockIdx.x;
    const int n = bid >> 6, h0 = (bid & 63) * 2;
    const int tid = threadIdx.x;
    const float* sp = src + (size_t)n*CH*HW + h0*WPIX + tid;
    #pragma unroll
    for (int ic = 0; ic < 16; ++ic)
        ls[ic][tid] = sp[(size_t)ic*HW];
    __syncthreads();
    unsigned short tmp[16];
    #pragma unroll
    for (int ic = 0; ic < 16; ++ic)
        tmp[ic] = f2bf(ls[ic][tid]);
    u16x8* d = (u16x8*)(dst + ((size_t)n*HW + h0*WPIX)*16);
    d[tid*2]     = *(u16x8*)&tmp[0];
    d[tid*2 + 1] = *(u16x8*)&tmp[8];
}

// ---------------- MFMA implicit-GEMM conv 3x3 pad 1 ------------------------------------
// Weights come prepacked (wpk): afr loaded global->register, coalesced, L2-hot.
// NC=3: input xT NHWC bf16; outputs q,k,v head-split bf16 (u16x2 packed stores).
// NC=1: input yH head-split bf16; output fp32 NCHW (harness layout).
template<int NC>
__global__ __launch_bounds__(256, NC == 3 ? 3 : 4) void conv_mfma_k(
    const unsigned short* __restrict__ xin,
    const unsigned short* __restrict__ wpk,   // [NC][5][64][8] bf16 fragments
    const float* __restrict__ b0, const float* __restrict__ b1,
    const float* __restrict__ b2,
    unsigned short* __restrict__ oq, unsigned short* __restrict__ ok,
    unsigned short* __restrict__ ov, float* __restrict__ ofp)
{
    __shared__ unsigned short xs[7*66*16];    // 14784 B (no weight LDS anymore)

    const int bid = blockIdx.x;
    const int n     = bid >> 6;
    const int h0    = ((bid >> 1) & 31) * 4;
    const int w0pix = (bid & 1) * 64;
    const int tid  = threadIdx.x;
    const int lane = tid & 63, wid = tid >> 6;
    const int lanelo = lane & 15, hi = lane >> 5, ichalf = (lane >> 4) & 1;
    const int quad = lane >> 4;
    const int b = n >> 6, tok = n & 63;

    // A fragments straight from global (uniform base + lane*16B -> coalesced)
    bf16x8 afr[NC][5];
    #pragma unroll
    for (int cv = 0; cv < NC; ++cv)
        #pragma unroll
        for (int ks = 0; ks < 5; ++ks)
            afr[cv][ks] = *(const bf16x8*)(wpk + ((cv*5 + ks)*64 + lane)*8);

    if constexpr (NC == 3) {
        // stage from NHWC xT: u16x8 chunks
        for (int c = tid; c < 7*66*2; c += 256) {
            int half = c & 1, col = (c >> 1) % 66, row = (c >> 1) / 66;
            int gh = h0 - 1 + row, gw = w0pix - 1 + col;
            u16x8 val = {0,0,0,0,0,0,0,0};
            if (row < 6 && (unsigned)gh < 128u && (unsigned)gw < 128u)
                val = *(const u16x8*)(xin + (((size_t)n*128 + gh)*128 + gw)*16 + half*8);
            int sw = half ^ ((col >> 2) & 1);
            *(u16x8*)&xs[(row*66 + col)*16 + sw*8] = val;
        }
    } else {
        // stage from head-split yH: position-major, 8 heads unrolled (addr math 1x/pos)
        const size_t tbase = ((size_t)(b*8)*64 + tok)*32768;
        for (int p = tid; p < 7*66; p += 256) {
            int row = p / 66, col = p - (p/66)*66;
            int gh = h0 - 1 + row, gw = w0pix - 1 + col;
            bool inb = (row < 6) && ((unsigned)gh < 128u) && ((unsigned)gw < 128u);
            const size_t poff = ((size_t)gh*128 + gw)*2;
            unsigned short* xp = &xs[(row*66 + col)*16];
            int swbase = (col >> 2) & 1;
            #pragma unroll
            for (int hh = 0; hh < 8; ++hh) {
                u16x2 val = {0, 0};
                if (inb)
                    val = *(const u16x2*)(xin + tbase + (size_t)hh*64*32768 + poff);
                int sw = (hh >> 2) ^ swbase;
                *(u16x2*)(xp + sw*8 + (hh & 3)*2) = val;
            }
        }
    }
    __syncthreads();

    const float* bps[3] = {b0, b1, b2};
    float biasr[NC][4];
    #pragma unroll
    for (int cv = 0; cv < NC; ++cv)
        #pragma unroll
        for (int j = 0; j < 4; ++j)
            biasr[cv][j] = bps[cv][quad*4 + j];

    #pragma unroll
    for (int t = 0; t < 4; ++t) {
        f32x4 acc[NC];
        #pragma unroll
        for (int cv = 0; cv < NC; ++cv)
            #pragma unroll
            for (int j = 0; j < 4; ++j) acc[cv][j] = biasr[cv][j];

        #pragma unroll
        for (int ks = 0; ks < 5; ++ks) {
            int tap = 2*ks + hi;
            int r = tap / 3, cc = tap - r*3;
            int srow = (tap == 9) ? 6 : (wid + r);
            int scol = t*16 + lanelo + cc;
            int sw = ichalf ^ ((scol >> 2) & 1);
            bf16x8 bfr = *(const bf16x8*)&xs[(srow*66 + scol)*16 + sw*8];
            #pragma unroll
            for (int cv = 0; cv < NC; ++cv)
                acc[cv] = __builtin_amdgcn_mfma_f32_16x16x32_bf16(
                              afr[cv][ks], bfr, acc[cv], 0, 0, 0);
        }

        const int pix = (h0 + wid)*WPIX + w0pix + t*16 + lanelo;
        if constexpr (NC == 3) {
            #pragma unroll
            for (int jp = 0; jp < 2; ++jp) {
                int hh = quad*2 + jp;
                size_t off = ((size_t)((b*8 + hh)*64 + tok))*32768 + (size_t)pix*2;
                u16x2 pq, pk, pv;
                pq[0] = f2bf(acc[0][jp*2]); pq[1] = f2bf(acc[0][jp*2+1]);
                pk[0] = f2bf(acc[1][jp*2]); pk[1] = f2bf(acc[1][jp*2+1]);
                pv[0] = f2bf(acc[2][jp*2]); pv[1] = f2bf(acc[2][jp*2+1]);
                *(u16x2*)(oq + off) = pq;
                *(u16x2*)(ok + off) = pk;
                *(u16x2*)(ov + off) = pv;
            }
        } else {
            float* op = ofp + ((size_t)n*16 + quad*4)*HW + pix;
            #pragma unroll
            for (int j = 0; j < 4; ++j)
                op[(size_t)j*HW] = acc[0][j];
        }
    }
}

// ---------------- QK^T partials, MFMA bf16 (layout-invariant over d) -------------------
// NSLICE_QK=64 -> 1024 blocks (4/CU). Each block: 64x64 scores over 512 d (8 chunks).
__global__ __launch_bounds__(256, 4) void qk_mfma_k(
    const unsigned short* __restrict__ qA, const unsigned short* __restrict__ kA,
    float* __restrict__ partial)
{
    __shared__ unsigned short qs[64*64];
    __shared__ unsigned short ks[64*64];
    const int slice = blockIdx.x & (NSLICE_QK-1);
    const int bh = blockIdx.x >> 6;
    const int tid = threadIdx.x;
    const int lane = tid & 63;
    const int grp = lane >> 4, lanelo = lane & 15;
    const size_t base = (size_t)bh*64*32768 + (size_t)slice*512;

    f32x4 acc[4][4];
    #pragma unroll
    for (int i = 0; i < 4; ++i)
        #pragma unroll
        for (int j = 0; j < 4; ++j)
            #pragma unroll
            for (int e = 0; e < 4; ++e) acc[i][j][e] = 0.f;

    for (int ch = 0; ch < 8; ++ch) {
        __syncthreads();
        for (int i = tid; i < 512; i += 256) {
            int t = i >> 3, dp = i & 7;
            int sw = dp ^ (t & 7);
            const size_t g = base + (size_t)t*32768 + ch*64 + dp*8;
            *(u16x8*)&qs[t*64 + sw*8] = *(const u16x8*)(qA + g);
            *(u16x8*)&ks[t*64 + sw*8] = *(const u16x8*)(kA + g);
        }
        __syncthreads();
        #pragma unroll
        for (int kh = 0; kh < 2; ++kh) {
            const int dchunk = kh*4 + grp;
            bf16x8 af[4], bf[4];
            #pragma unroll
            for (int ti = 0; ti < 4; ++ti) {
                int t = ti*16 + lanelo;
                int sw = dchunk ^ (t & 7);
                af[ti] = *(const bf16x8*)&qs[t*64 + sw*8];
                bf[ti] = *(const bf16x8*)&ks[t*64 + sw*8];
            }
            #pragma unroll
            for (int ti = 0; ti < 4; ++ti)
                #pragma unroll
                for (int si = 0; si < 4; ++si)
                    acc[ti][si] = __builtin_amdgcn_mfma_f32_16x16x32_bf16(
                                      af[ti], bf[si], acc[ti][si], 0, 0, 0);
        }
    }

    float* pp = partial + (size_t)blockIdx.x * 4096;   // [bh][slice][t][s]
    #pragma unroll
    for (int ti = 0; ti < 4; ++ti)
        #pragma unroll
        for (int si = 0; si < 4; ++si)
            #pragma unroll
            for (int j = 0; j < 4; ++j) {
                int row = ti*16 + grp*4 + j;
                int col = si*16 + lanelo;
                pp[row*64 + col] = acc[ti][si][j];
            }
}

// ---------------- reduce partials -> logits --------------------------------------------
__global__ __launch_bounds__(256) void reduce_logits_k(
    const float* __restrict__ partial, float* __restrict__ logits)
{
    int idx = blockIdx.x * 256 + threadIdx.x;
    int bh = idx >> 12, ts = idx & 4095;
    float s = 0.f;
    for (int sl = 0; sl < NSLICE_QK; ++sl)
        s += partial[((size_t)(bh*NSLICE_QK) + sl)*4096 + ts];
    logits[idx] = s;
}

// ---------------- causal softmax -> bf16 att[bh][t][s] ---------------------------------
__global__ __launch_bounds__(256) void softmax_k(
    const float* __restrict__ logits, unsigned short* __restrict__ att)
{
    const int bh = blockIdx.x;
    const int tid = threadIdx.x;
    const int t = tid >> 2, sg = tid & 3;
    float r[16];
    #pragma unroll
    for (int i = 0; i < 16; ++i) {
        int s = sg*16 + i;
        float val = logits[bh*4096 + t*64 + s] * SCALE_ATT;
        r[i] = (s <= t) ? val : -1e30f;
    }
    float m = r[0];
    #pragma unroll
    for (int i = 1; i < 16; ++i) m = fmaxf(m, r[i]);
    m = fmaxf(m, __shfl_xor(m, 1));
    m = fmaxf(m, __shfl_xor(m, 2));
    float sum = 0.f;
    #pragma unroll
    for (int i = 0; i < 16; ++i) {
        int s = sg*16 + i;
        r[i] = (s <= t) ? expf(r[i] - m) : 0.f;
        sum += r[i];
    }
    sum += __shfl_xor(sum, 1);
    sum += __shfl_xor(sum, 2);
    const float inv = 1.f / sum;
    #pragma unroll
    for (int i = 0; i < 16; ++i) {
        int s = sg*16 + i;
        att[bh*4096 + t*64 + s] = f2bf(r[i] * inv);
    }
}

// ---------------- y = att @ v via MFMA --------------------------------------------------
__global__ __launch_bounds__(256, 3) void attv_mfma_k(
    const unsigned short* __restrict__ vH,   // [bh][s][d]
    const unsigned short* __restrict__ att,  // [bh][t][s]
    unsigned short* __restrict__ yH)         // [bh][t][d]
{
    __shared__ unsigned short vs[256*64];    // [d_local][s] swizzled, 32 KB
    __shared__ unsigned short as[64*64];     // [t][s] swizzled, 8 KB

    const int blk = blockIdx.x;
    const int pt = blk & 127;
    const int bh = blk >> 7;
    const int tid = threadIdx.x;
    const int lane = tid & 63, wid = tid >> 6;
    const int grp = lane >> 4, lanelo = lane & 15;

    const size_t vbase = (size_t)bh*64*32768 + (size_t)pt*256;

    #pragma unroll
    for (int j = 0; j < 8; ++j) {
        int i = tid + j*256;
        int s = i & 63, dc = i >> 6;
        u16x8 val = *(const u16x8*)(vH + vbase + (size_t)s*32768 + dc*8);
        #pragma unroll
        for (int e = 0; e < 8; ++e) {
            int d = dc*8 + e;
            int cs = (s >> 3) ^ (d & 7);
            vs[d*64 + cs*8 + (s & 7)] = val[e];
        }
    }
    #pragma unroll
    for (int j = 0; j < 2; ++j) {
        int i = tid + j*256;
        int t = i >> 3, ch = i & 7;
        int cs = ch ^ (t & 7);
        *(u16x8*)&as[t*64 + cs*8] =
            *(const u16x8*)(att + (size_t)bh*4096 + t*64 + ch*8);
    }
    __syncthreads();

    bf16x8 af[4][2];
    #pragma unroll
    for (int mi = 0; mi < 4; ++mi)
        #pragma unroll
        for (int ki = 0; ki < 2; ++ki) {
            int t = mi*16 + lanelo;
            int cs = (ki*4 + grp) ^ (t & 7);
            af[mi][ki] = *(const bf16x8*)&as[t*64 + cs*8];
        }

    f32x4 acc[4][4];   // [mi][ni]
    #pragma unroll
    for (int mi = 0; mi < 4; ++mi)
        #pragma unroll
        for (int ni = 0; ni < 4; ++ni)
            #pragma unroll
            for (int e = 0; e < 4; ++e) acc[mi][ni][e] = 0.f;

    #pragma unroll
    for (int ki = 0; ki < 2; ++ki)
        #pragma unroll
        for (int ni = 0; ni < 4; ++ni) {
            int d = wid*64 + ni*16 + lanelo;
            int cs = (ki*4 + grp) ^ (d & 7);
            bf16x8 bf = *(const bf16x8*)&vs[d*64 + cs*8];
            #pragma unroll
            for (int mi = 0; mi < 4; ++mi)
                acc[mi][ni] = __builtin_amdgcn_mfma_f32_16x16x32_bf16(
                                  af[mi][ki], bf, acc[mi][ni], 0, 0, 0);
        }

    #pragma unroll
    for (int mi = 0; mi < 4; ++mi)
        #pragma unroll
        for (int ni = 0; ni < 4; ++ni) {
            int t = mi*16 + grp*4;
            int d = wid*64 + ni*16 + lanelo;
            #pragma unroll
            for (int j = 0; j < 4; ++j)
                yH[(size_t)bh*64*32768 + (size_t)(t + j)*32768 + pt*256 + d]
                    = f2bf(acc[mi][ni][j]);
        }
}

// ---------------- launch ---------------------------------------------------------------
extern "C" void kernel_launch(void* const* d_in, const int* in_sizes, int n_in,
                              void* d_out, int out_size, void* d_ws, size_t ws_size,
                              hipStream_t stream)
{
    const float* x   = (const float*)d_in[0];
    const float* wq  = (const float*)d_in[1];
    const float* bq  = (const float*)d_in[2];
    const float* wk  = (const float*)d_in[3];
    const float* bk  = (const float*)d_in[4];
    const float* wvv = (const float*)d_in[5];
    const float* bv  = (const float*)d_in[6];
    const float* wo  = (const float*)d_in[7];
    const float* bo  = (const float*)d_in[8];
    float* out = (float*)d_out;

    unsigned short* xT = (unsigned short*)d_ws;        // 64 MB each
    unsigned short* qA = xT + 33554432;
    unsigned short* kA = qA + 33554432;
    unsigned short* vH = kA + 33554432;
    unsigned short* yH = vH + 33554432;
    float* partial = (float*)(yH + 33554432);          // 16*64*4096 f32 = 16 MB
    float* logits  = partial + 16*NSLICE_QK*4096;      // 256 KB
    unsigned short* att_bf = (unsigned short*)(logits + 65536);   // 128 KB
    unsigned short* wpk = att_bf + 65536;              // 4*2560 bf16 = 20 KB

    prepack_w_k<<<40, 256, 0, stream>>>(wq, wk, wvv, wo, wpk);
    nchw2nhwc_k<<<8192, 256, 0, stream>>>(x, xT);
    conv_mfma_k<3><<<8192, 256, 0, stream>>>(xT, wpk, bq, bk, bv,
                                             qA, kA, vH, nullptr);
    qk_mfma_k<<<16*NSLICE_QK, 256, 0, stream>>>(qA, kA, partial);
    reduce_logits_k<<<256, 256, 0, stream>>>(partial, logits);
    softmax_k<<<16, 256, 0, stream>>>(logits, att_bf);
    attv_mfma_k<<<2048, 256, 0, stream>>>(vH, att_bf, yH);
    conv_mfma_k<1><<<8192, 256, 0, stream>>>(yH, wpk + 3*2560, bo, nullptr, nullptr,
                                             nullptr, nullptr, nullptr, out);
}